// Round 11
// baseline (183.375 us; speedup 1.0000x reference)
//
#include <hip/hip_runtime.h>
#include <stdint.h>

// MHA forward.  Inputs FP32, output FP32.  Compute: bf16 MFMA, fp32 accumulate.
// B=2,S=2048,D=1024,H=16,HD=64.
//
// hs=16 fast path (4 launches; ~80us of wall is harness-fixed overhead):
//   prep: x fp32->bf16 + Wo transpose + Wq/Wk/Wv col transpose (one kernel)
//   k2  : xb @ WT3sl^T -> Qsl (pre-scaled 0.125*log2e) / Ksl, VTsl
//   k3  : attn v12 (3-buffer pipelined: QK(kt+1) || softmax(kt) || PV(kt))
//   k4  : A2sl @ WoT^T + bo -> fp32 out
//
// gemm v5 (this round): BK 32 -> 64.  r10's swizzle cut FETCH 40->28.8MB but
// time barely moved -- k2's cost is the per-k-step vmcnt(0) drain at the
// barrier (32 steps x exposed DMA latency; 2-3 resident blocks only partly
// cover it).  BK=64: compute per step doubles (32 MFMA + 16 ds_read_b128),
// drains halve (16 steps), DMA hide window ~2x.  LDS dbuf = 64KB -> still
// 2 blocks/CU (the m132 BK=128 occupancy cliff does NOT trigger).  Layout:
// row = 8 x 16B chunks, CPR=8 XOR swizzle (same pattern as attn lsK); 4
// staged chunks/thread/matrix.  XCD-chunk swizzle kept (FETCH win is real).

typedef unsigned short u16;
typedef __attribute__((ext_vector_type(8))) short bf16x8;
typedef __attribute__((ext_vector_type(4))) float f32x4;

#define MFMA_BF16(a, b, c) __builtin_amdgcn_mfma_f32_16x16x32_bf16((a), (b), (c), 0, 0, 0)
#define QSCALE 0.18033688011112042f  // 0.125 * log2(e)

#if __has_builtin(__builtin_amdgcn_exp2f)
#define EXP2(x) __builtin_amdgcn_exp2f(x)
#else
#define EXP2(x) exp2f(x)
#endif

__device__ __forceinline__ u16 f2bf(float f) {  // RNE
  union { float f; unsigned int u; } x; x.f = f;
  unsigned int r = x.u + 0x7fffu + ((x.u >> 16) & 1u);
  return (u16)(r >> 16);
}
__device__ __forceinline__ bf16x8 pack8(float4 a, float4 b) {
  bf16x8 r;
  r[0] = (short)f2bf(a.x); r[1] = (short)f2bf(a.y);
  r[2] = (short)f2bf(a.z); r[3] = (short)f2bf(a.w);
  r[4] = (short)f2bf(b.x); r[5] = (short)f2bf(b.y);
  r[6] = (short)f2bf(b.z); r[7] = (short)f2bf(b.w);
  return r;
}
__device__ __forceinline__ void gload_lds16(const u16* g, u16* l) {
  __builtin_amdgcn_global_load_lds((__attribute__((address_space(1))) void*)g,
                                   (__attribute__((address_space(3))) void*)l, 16, 0, 0);
}

template <int CPR>
__device__ __forceinline__ int sw_off(int r, int c) {
  return (r * CPR + (c ^ (r & (CPR - 1)))) * 8;
}

// ---- fused prep: x->bf16 + Wo transpose + Wq/Wk/Wv transpose (hs=16 path) ----
__global__ __launch_bounds__(1024) void prep(
    const float* __restrict__ x, u16* __restrict__ xb,
    const float* __restrict__ Wq, const float* __restrict__ Wk,
    const float* __restrict__ Wv, const float* __restrict__ Wo,
    u16* __restrict__ WoT, u16* __restrict__ WT3) {
  const int bxg = blockIdx.x, by = blockIdx.y;
  if (bxg >= 128) {
    const int blk = (bxg - 128) * 32 + by;  // 0..511
    const int tid = threadIdx.y * 32 + threadIdx.x;
    const size_t i = ((size_t)blk * 1024 + tid) * 8;
    const float4 a = *(const float4*)&x[i];
    const float4 b2 = *(const float4*)&x[i + 4];
    *(bf16x8*)&xb[i] = pack8(a, b2);
    return;
  }
  __shared__ u16 t[32][33];
  const float* W;
  u16* T;
  int j0, wcol;
  if (bxg < 32) {
    j0 = bxg * 32; wcol = j0; W = Wo; T = WoT;
  } else {
    j0 = (bxg - 32) * 32;  // 0..3071
    const int g = j0 >> 10;
    W = (g == 0) ? Wq : (g == 1) ? Wk : Wv;
    T = WT3;
    wcol = j0 & 1023;
  }
  const int k0 = by * 32;
  t[threadIdx.y][threadIdx.x] =
      f2bf(W[(size_t)(k0 + threadIdx.y) * 1024 + wcol + threadIdx.x]);
  __syncthreads();
  T[(size_t)(j0 + threadIdx.y) * 1024 + k0 + threadIdx.x] = t[threadIdx.x][threadIdx.y];
}

// ---- fallback-path helpers (hs<16) ----
__global__ __launch_bounds__(256) void x_to_bf16(const float* __restrict__ x,
                                                 u16* __restrict__ xb) {
  const size_t i = ((size_t)blockIdx.x * 256 + threadIdx.x) * 8;
  const float4 a = *(const float4*)&x[i];
  const float4 b = *(const float4*)&x[i + 4];
  *(bf16x8*)&xb[i] = pack8(a, b);
}

__global__ void transpose_cols(const float* __restrict__ W0, const float* __restrict__ W1,
                               const float* __restrict__ W2, u16* __restrict__ T,
                               int h0, int hsx64) {
  __shared__ u16 t[32][33];
  const int j0 = blockIdx.x * 32;
  const int g = j0 / hsx64;
  const float* W = (g == 0) ? W0 : (g == 1) ? W1 : W2;
  const int wc0 = h0 * 64 + (j0 % hsx64);
  const int k0 = blockIdx.y * 32;
  t[threadIdx.y][threadIdx.x] =
      f2bf(W[(size_t)(k0 + threadIdx.y) * 1024 + wc0 + threadIdx.x]);
  __syncthreads();
  T[(size_t)(j0 + threadIdx.y) * 1024 + k0 + threadIdx.x] = t[threadIdx.x][threadIdx.y];
}

// ---- k2/k4: C = A[M][K] @ BT[N][K]^T, 128x128 tile, BK=64 dbuf + XCD swizzle ----
template <int MODE, int AF32>
__global__ __launch_bounds__(256, 2) void gemm_bt(
    const void* __restrict__ Av, const u16* __restrict__ BT,
    void* __restrict__ C0v, u16* __restrict__ C1, u16* __restrict__ C2,
    const float* __restrict__ bias, int M, int N, int K, int hs, int h0) {
  __shared__ __align__(16) u16 lsA[2][128 * 64];
  __shared__ __align__(16) u16 lsB[2][128 * 64];
  const int tid = threadIdx.x, lane = tid & 63, wv = tid >> 6;
  const int quad = lane >> 4, l16 = lane & 15;
  // XCD-chunk swizzle (bijective when nwg%8==0): each XCD gets a contiguous
  // run of linear ids -> with x-fast order, full m-rows per XCD share
  // A-row-panels in that XCD's L2.  [r10: FETCH 40->28.8MB]
  const int nwg = gridDim.x * gridDim.y;
  int lin = blockIdx.y * gridDim.x + blockIdx.x;
  if ((nwg & 7) == 0) lin = (lin & 7) * (nwg >> 3) + (lin >> 3);
  const int m0 = (lin / gridDim.x) * 128, n0 = (lin % gridDim.x) * 128;
  const int wm = (wv >> 1) * 64, wn = (wv & 1) * 64;
  const int hs64 = hs * 64;
  f32x4 acc[4][4] = {};

  if constexpr (!AF32) {
    // per-tile staging: 128 rows x 64 cols = 1024 x 16B chunks; 4/thread/matrix
    auto stage = [&](int kt, int bb) {
      const int k0 = kt << 6;
#pragma unroll
      for (int c = 0; c < 4; ++c) {
        const int P = c * 256 + tid, r = P >> 3;
        const int gcol = ((P & 7) ^ (r & 7)) * 8;
        gload_lds16((const u16*)Av + (size_t)(m0 + r) * K + k0 + gcol,
                    &lsA[bb][(c * 256 + wv * 64) * 8]);
        gload_lds16(BT + (size_t)(n0 + r) * K + k0 + gcol,
                    &lsB[bb][(c * 256 + wv * 64) * 8]);
      }
    };
    stage(0, 0);
    __syncthreads();  // tile 0 landed
    const int nk = K >> 6;
    for (int kt = 0; kt < nk; ++kt) {
      const int buf = kt & 1;
      if (kt + 1 < nk) stage(kt + 1, buf ^ 1);  // DMA next tile BEFORE compute
#pragma unroll
      for (int ks = 0; ks < 2; ++ks) {
        bf16x8 af[4], bfr[4];
#pragma unroll
        for (int i = 0; i < 4; ++i)
          af[i] = *(const bf16x8*)&lsA[buf][sw_off<8>(wm + i * 16 + l16, ks * 4 + quad)];
#pragma unroll
        for (int j = 0; j < 4; ++j)
          bfr[j] = *(const bf16x8*)&lsB[buf][sw_off<8>(wn + j * 16 + l16, ks * 4 + quad)];
#pragma unroll
        for (int i = 0; i < 4; ++i)
#pragma unroll
          for (int j = 0; j < 4; ++j) acc[i][j] = MFMA_BF16(af[i], bfr[j], acc[i][j]);
      }
      __syncthreads();  // drains vmcnt (tile kt+1 landed) + all reads of buf done
    }
  } else {
    // fallback reg-staged path (hs<16 only), single-buffered, BK=32
    for (int k0 = 0; k0 < K; k0 += 32) {
      bf16x8 va[2], vb[2];
#pragma unroll
      for (int c = 0; c < 2; ++c) {
        const int P = c * 256 + tid, r = P >> 2, cc = P & 3;
        const float* Af = (const float*)Av;
        const float4 a0 = *(const float4*)&Af[(size_t)(m0 + r) * K + k0 + cc * 8];
        const float4 a1 = *(const float4*)&Af[(size_t)(m0 + r) * K + k0 + cc * 8 + 4];
        va[c] = pack8(a0, a1);
        vb[c] = *(const bf16x8*)&BT[(size_t)(n0 + r) * K + k0 + cc * 8];
      }
      __syncthreads();
#pragma unroll
      for (int c = 0; c < 2; ++c) {
        const int P = c * 256 + tid, r = P >> 2, cc = P & 3;
        *(bf16x8*)&lsA[0][sw_off<4>(r, cc)] = va[c];
        *(bf16x8*)&lsB[0][sw_off<4>(r, cc)] = vb[c];
      }
      __syncthreads();
      bf16x8 af[4], bfr[4];
#pragma unroll
      for (int i = 0; i < 4; ++i)
        af[i] = *(const bf16x8*)&lsA[0][sw_off<4>(wm + i * 16 + l16, quad)];
#pragma unroll
      for (int j = 0; j < 4; ++j)
        bfr[j] = *(const bf16x8*)&lsB[0][sw_off<4>(wn + j * 16 + l16, quad)];
#pragma unroll
      for (int i = 0; i < 4; ++i)
#pragma unroll
        for (int j = 0; j < 4; ++j) acc[i][j] = MFMA_BF16(af[i], bfr[j], acc[i][j]);
    }
  }

  if constexpr (MODE == 3) {
#pragma unroll
    for (int j = 0; j < 4; ++j) {
      const int n = n0 + wn + j * 16 + l16;  // region constant over i,r
#pragma unroll
      for (int i = 0; i < 4; ++i) {
        const int mb = m0 + wm + i * 16 + quad * 4;  // 4-aligned, no 2048-cross
        const int b = mb >> 11, s0 = mb & 2047;
        if (n < hs64) {
#pragma unroll
          for (int r = 0; r < 4; ++r)
            ((u16*)C0v)[((size_t)b * 2048 + s0 + r) * hs64 + n] =
                f2bf(acc[i][j][r] * QSCALE);
        } else if (n < 2 * hs64) {
#pragma unroll
          for (int r = 0; r < 4; ++r)
            C1[((size_t)b * 2048 + s0 + r) * hs64 + (n - hs64)] = f2bf(acc[i][j][r]);
        } else {
          const int nn = n - 2 * hs64;  // V: r-adjacent = s-consecutive -> pack 8B
          uint2 o;
          o.x = (unsigned)f2bf(acc[i][j][0]) | ((unsigned)f2bf(acc[i][j][1]) << 16);
          o.y = (unsigned)f2bf(acc[i][j][2]) | ((unsigned)f2bf(acc[i][j][3]) << 16);
          *(uint2*)&C2[((size_t)(b * hs + (nn >> 6)) * 64 + (nn & 63)) * 2048 + s0] = o;
        }
      }
    }
  } else {
#pragma unroll
    for (int i = 0; i < 4; ++i)
#pragma unroll
      for (int j = 0; j < 4; ++j) {
        const int n = n0 + wn + j * 16 + l16;
        float bv = 0.f;
        if constexpr (MODE == 1) bv = bias[n];
#pragma unroll
        for (int r = 0; r < 4; ++r) {
          const int m = m0 + wm + i * 16 + quad * 4 + r;
          const int b = (m >= hs * 128) ? 1 : 0;
          const int rp = m - b * hs * 128;
          ((float*)C0v)[(size_t)(b * 2048 + h0 * 128 + rp) * 1024 + n] =
              acc[i][j][r] + bv;
        }
      }
  }
}

// ---- k3: attn v12 (pipelined; unchanged from r8/r10) ----
__global__ __launch_bounds__(256, 2) void attn_fwd(
    const u16* __restrict__ Qsl, const u16* __restrict__ Ksl,
    const u16* __restrict__ VTsl, u16* __restrict__ A2sl, int hs) {
  __shared__ __align__(16) u16 lsK[3][64 * 64];  // [key][hd] CPR=8; [0..1] dead
                                                 // after kt loop -> f32 O scratch
  __shared__ __align__(16) u16 lsV[3][64 * 64];  // [hd][key] CPR=8
  __shared__ __align__(16) u16 lsP[4][16 * 64];  // per-wave P^T, 128B rows, XOR-swz
  __shared__ __align__(16) float scrl[64];
  const int tid = threadIdx.x, lane = tid & 63, wv = tid >> 6;
  const int quad = lane >> 4, l16 = lane & 15;
  const int grp = wv >> 1, wq = wv & 1;

  // bijective XCD-chunk swizzle (gridDim.x % 8 == 0)
  const int cpx = gridDim.x >> 3;
  const int w = (blockIdx.x & 7) * cpx + (blockIdx.x >> 3);
  const int bh = w >> 4, bx = w & 15;

  const int b = (bh >= hs) ? 1 : 0, hh = bh - b * hs;
  const int hs64 = hs * 64;
  const u16* Qb = Qsl + (size_t)b * 2048 * hs64;
  const u16* Kb = Ksl + (size_t)b * 2048 * hs64;
  const u16* Vb = VTsl + (size_t)(b * hs + hh) * 64 * 2048;
  u16* A2b = A2sl + (size_t)(b * hs + hh) * 2048 * 64;
  u16* lsPw = &lsP[wv][0];
  float* scro = (float*)&lsK[0][0];  // 16KB spans lsK[0..1]

  bf16x8 ones;
#pragma unroll
  for (int i = 0; i < 8; ++i) ones[i] = (short)0x3F80;

  const int prow = l16 >> 1;       // lsP row sub-index / XOR mask
  const int pb0 = (l16 & 1) << 2;  // q&1 selects 32-u16 half of the 128B row

  // constant per-thread staging geometry
  const int Pa = tid, ra = Pa >> 3, ca = (Pa & 7) ^ (ra & 7);
  const int Pb2 = 256 + tid, rb = Pb2 >> 3, cb = (Pb2 & 7) ^ (rb & 7);
  const size_t kTileStep = (size_t)64 * hs64;
  const u16* const kBa = Kb + (size_t)ra * hs64 + hh * 64 + ca * 8;
  const u16* const kBb = Kb + (size_t)rb * hs64 + hh * 64 + cb * 8;
  const u16* const vBa = Vb + (size_t)ra * 2048 + ca * 8;
  const u16* const vBb = Vb + (size_t)rb * 2048 + cb * 8;
  const int dA = (wv * 64) * 8;
  const int dB = (256 + wv * 64) * 8;

  for (int half = 0; half < 2; ++half) {
    const int qt = (half == 0) ? bx : 31 - bx;
    const int q0 = qt * 64;

    bf16x8 qf[2][2];
#pragma unroll
    for (int j = 0; j < 2; ++j)
#pragma unroll
      for (int ks = 0; ks < 2; ++ks)
        qf[j][ks] = *(const bf16x8*)&Qb[(size_t)(q0 + wq * 32 + j * 16 + l16) * hs64 +
                                        hh * 64 + ks * 32 + quad * 8];

    f32x4 acc_o[2][4] = {};
    f32x4 acc_l[2] = {};

    const u16* pkA = kBa;
    const u16* pkB = kBb;
    const u16* pvA = vBa;
    const u16* pvB = vBb;
    int bc = 0, bn = 1, bf_ = 2;

    auto stage = [&](int bs) {  // DMA one K/V tile, advance source pointers
      gload_lds16(pkA, &lsK[bs][dA]);
      gload_lds16(pkB, &lsK[bs][dB]);
      gload_lds16(pvA, &lsV[bs][dA]);
      gload_lds16(pvB, &lsV[bs][dB]);
      pkA += kTileStep; pkB += kTileStep; pvA += 64; pvB += 64;
    };
    auto qk = [&](int bK, f32x4 (&S)[2][2]) {  // S^T = K Q^T
#pragma unroll
      for (int j = 0; j < 2; ++j)
#pragma unroll
        for (int nj = 0; nj < 2; ++nj) S[j][nj] = f32x4{0.f, 0.f, 0.f, 0.f};
#pragma unroll
      for (int ks = 0; ks < 2; ++ks)
#pragma unroll
        for (int nj = 0; nj < 2; ++nj) {
          const bf16x8 kf = *(const bf16x8*)
              &lsK[bK][sw_off<8>(grp * 32 + nj * 16 + l16, ks * 4 + quad)];
          S[0][nj] = MFMA_BF16(kf, qf[0][ks], S[0][nj]);
          S[1][nj] = MFMA_BF16(kf, qf[1][ks], S[1][nj]);
        }
    };
    auto smpv = [&](f32x4 (&S)[2][2], int bV, bool domask) {  // softmax + PV + l
#pragma unroll
      for (int j = 0; j < 2; ++j) {
        const int grow = wq * 32 + j * 16 + l16;
#pragma unroll
        for (int nj = 0; nj < 2; ++nj) {
#pragma unroll
          for (int r = 0; r < 4; ++r) {
            float p = EXP2(S[j][nj][r]);
            if (domask) {
              const int keyb = grp * 32 + nj * 16 + quad * 4;
              p = (keyb + r > grow) ? 0.f : p;
            }
            S[j][nj][r] = p;
          }
          union { float f; unsigned int u; } t0, t1, t2, t3;
          t0.f = S[j][nj][0]; t1.f = S[j][nj][1];
          t2.f = S[j][nj][2]; t3.f = S[j][nj][3];
          uint2 wpk;
          wpk.x = (t0.u >> 16) | (t1.u & 0xFFFF0000u);
          wpk.y = (t2.u >> 16) | (t3.u & 0xFFFF0000u);
          const int row = j * 8 + prow;
          const int chunk = (pb0 + 2 * nj + (quad >> 1)) ^ prow;
          *(uint2*)&lsPw[row * 64 + chunk * 8 + (quad & 1) * 4] = wpk;
        }
      }
      bf16x8 pf[2];
#pragma unroll
      for (int j = 0; j < 2; ++j) {
        const int row = j * 8 + prow;
        const int chunk = (pb0 + quad) ^ prow;
        pf[j] = *(const bf16x8*)&lsPw[row * 64 + chunk * 8];
        acc_l[j] = MFMA_BF16(ones, pf[j], acc_l[j]);
      }
#pragma unroll
      for (int njo = 0; njo < 4; ++njo) {
        const bf16x8 vf = *(const bf16x8*)
            &lsV[bV][sw_off<8>(njo * 16 + l16, grp * 4 + quad)];
        acc_o[0][njo] = MFMA_BF16(vf, pf[0], acc_o[0][njo]);
        acc_o[1][njo] = MFMA_BF16(vf, pf[1], acc_o[1][njo]);
      }
    };
    // one pipelined iteration: Sc = S(kt) ready; computes S(kt+1) into Sn
    auto step = [&](f32x4 (&Sc)[2][2], f32x4 (&Sn)[2][2], int kt) {
      __syncthreads();                 // DMA(kt+1) landed in bn; bf_ reads done
      if (kt + 2 <= qt) stage(bf_);    // DMA(kt+2) -> bf_, in flight this iter
      qk(bn, Sn);                      // QK(kt+1): DS+MFMA
      smpv(Sc, bc, false);             // softmax(kt): VALU (indep) + PV(kt)
      const int t = bc; bc = bn; bn = bf_; bf_ = t;
    };

    __syncthreads();   // prev half fully consumed (incl. scro region)
    stage(0);          // tile 0 -> buf 0
    __syncthreads();   // tile 0 landed
    if (qt >= 1) stage(1);  // tile 1 -> buf 1, in flight under QK(0)

    f32x4 sA[2][2], sB[2][2];
    qk(0, sA);  // S(0)

    int kt = 0;
    while (kt + 1 < qt) { step(sA, sB, kt); step(sB, sA, kt + 1); kt += 2; }
    bool curA = true;
    if (kt < qt) { step(sA, sB, kt); curA = false; }
    // tail: diagonal tile qt (masked); V(qt) is in bc after rotation
    if (curA) smpv(sA, bc, true); else smpv(sB, bc, true);

    // combine: exact partial sums (no-max softmax needs no rescale)
    __syncthreads();  // all lsK/lsV reads done -> scro region free
    if (grp == 1) {
#pragma unroll
      for (int j = 0; j < 2; ++j) {
#pragma unroll
        for (int njo = 0; njo < 4; ++njo) {
          const int ch = (njo * 4 + quad) ^ l16;
          *(f32x4*)&scro[(size_t)(wq * 32 + j * 16 + l16) * 64 + ch * 4] =
              acc_o[j][njo];
        }
        if (quad == 0) scrl[wq * 32 + j * 16 + l16] = acc_l[j][0];
      }
    }
    __syncthreads();
    if (grp == 0) {
#pragma unroll
      for (int j = 0; j < 2; ++j) {
        const int ql = wq * 32 + j * 16 + l16;
        const float inv = 1.0f / (acc_l[j][0] + scrl[ql]);
#pragma unroll
        for (int njo = 0; njo < 4; ++njo) {
          const int ch = (njo * 4 + quad) ^ l16;
          const f32x4 ob = *(const f32x4*)&scro[(size_t)ql * 64 + ch * 4];
          uint2 o;
          o.x = (unsigned)f2bf((acc_o[j][njo][0] + ob[0]) * inv) |
                ((unsigned)f2bf((acc_o[j][njo][1] + ob[1]) * inv) << 16);
          o.y = (unsigned)f2bf((acc_o[j][njo][2] + ob[2]) * inv) |
                ((unsigned)f2bf((acc_o[j][njo][3] + ob[3]) * inv) << 16);
          *(uint2*)&A2b[(size_t)(q0 + ql) * 64 + njo * 16 + quad * 4] = o;
        }
      }
    }
  }
}

// ---------------- launcher ----------------
extern "C" void kernel_launch(void* const* d_in, const int* in_sizes, int n_in,
                              void* d_out, int out_size, void* d_ws, size_t ws_size,
                              hipStream_t stream) {
  (void)in_sizes; (void)n_in; (void)out_size;
  const float* x  = (const float*)d_in[0];
  const float* Wq = (const float*)d_in[1];
  const float* Wk = (const float*)d_in[2];
  const float* Wv = (const float*)d_in[3];
  const float* Wo = (const float*)d_in[4];
  const float* bo = (const float*)d_in[5];
  float* out = (float*)d_out;
  char* ws = (char*)d_ws;
  const size_t MB = 1024 * 1024;
  const size_t KB = 1024;

  int hs = 2;
  if      (ws_size >= 2 * MB + 16 * 2432 * KB) hs = 16;
  else if (ws_size >= 2 * MB +  8 * 2432 * KB) hs = 8;
  else if (ws_size >= 2 * MB +  4 * 2432 * KB) hs = 4;

  u16* WoT   = (u16*)(ws);
  u16* Ksl   = (u16*)(ws + 2 * MB);
  u16* VTsl  = (u16*)(ws + 2 * MB + (size_t)hs *  512 * KB);
  u16* A2sl  = (u16*)(ws + 2 * MB + (size_t)hs * 1024 * KB);
  u16* WT3sl = (u16*)(ws + 2 * MB + (size_t)hs * 1536 * KB);
  u16* Qsl   = (u16*)(ws + 2 * MB + (size_t)hs * 1920 * KB);

  if (hs == 16) {
    u16* xb = A2sl;  // aliases A2sl: consumed by k2, overwritten by k3
    prep<<<dim3(144, 32), dim3(32, 32), 0, stream>>>(x, xb, Wq, Wk, Wv, Wo, WoT, WT3sl);
    gemm_bt<3, 0><<<dim3(24, 32), 256, 0, stream>>>(
        (const void*)xb, WT3sl, (void*)Qsl, Ksl, VTsl, nullptr, 4096, 3072, 1024, 16, 0);
    attn_fwd<<<dim3(512), 256, 0, stream>>>(Qsl, Ksl, VTsl, A2sl, 16);
    gemm_bt<1, 0><<<dim3(8, 32), 256, 0, stream>>>(
        (const void*)A2sl, WoT, (void*)out, nullptr, nullptr, bo, 4096, 1024, 1024, 16, 0);
  } else {
    transpose_cols<<<dim3(32, 32), dim3(32, 32), 0, stream>>>(Wo, Wo, Wo, WoT, 0, 1024);
    for (int h0 = 0; h0 < 16; h0 += hs) {
      transpose_cols<<<dim3(6 * hs, 32), dim3(32, 32), 0, stream>>>(Wq, Wk, Wv, WT3sl, h0, hs * 64);
      gemm_bt<3, 1><<<dim3((3 * hs) / 2, 32), 256, 0, stream>>>(
          (const void*)x, WT3sl, (void*)Qsl, Ksl, VTsl, nullptr, 4096, 3 * hs * 64, 1024, hs, h0);
      attn_fwd<<<dim3(16 * 2 * hs), 256, 0, stream>>>(Qsl, Ksl, VTsl, A2sl, hs);
      gemm_bt<1, 0><<<dim3(8, 2 * hs), 256, 0, stream>>>(
          (const void*)A2sl, WoT, (void*)out, nullptr, nullptr, bo, 2 * hs * 128, 1024, 1024, hs, h0);
    }
  }
}

// Round 12
// 175.966 us; speedup vs baseline: 1.0421x; 1.0421x over previous
//
#include <hip/hip_runtime.h>
#include <stdint.h>

// MHA forward.  Inputs FP32, output FP32.  Compute: bf16 MFMA, fp32 accumulate.
// B=2,S=2048,D=1024,H=16,HD=64.
//
// hs=16 fast path (4 launches; ~80us of wall is harness-fixed overhead):
//   prep: x fp32->bf16 + Wo transpose + Wq/Wk/Wv col transpose (one kernel)
//   k2  : xb @ WT3sl^T -> Qsl (pre-scaled 0.125*log2e) / Ksl, VTsl
//   k3  : attn v13 = v12 + T5 setprio around MFMA clusters
//   k4  : A2sl @ WoT^T + bo -> fp32 out
//
// r12: REVERT gemm to r10's BK=32 2-buffer (r11's BK=64 regressed: FETCH
// 28.8->54.4MB, the 8-row staging swizzle broke XCD-L2 grouping; k2 43->57us).
// BK=32 + XCD swizzle = local optimum of the 128^2 2-barrier family (43.2us).
// attn: + s_setprio(1) around QK and l+PV MFMA clusters (T5; guide m191 +4-7%
// on phase-diverse attn; blocks here are barrier-independent per CU).

typedef unsigned short u16;
typedef __attribute__((ext_vector_type(8))) short bf16x8;
typedef __attribute__((ext_vector_type(4))) float f32x4;

#define MFMA_BF16(a, b, c) __builtin_amdgcn_mfma_f32_16x16x32_bf16((a), (b), (c), 0, 0, 0)
#define QSCALE 0.18033688011112042f  // 0.125 * log2(e)

#if __has_builtin(__builtin_amdgcn_exp2f)
#define EXP2(x) __builtin_amdgcn_exp2f(x)
#else
#define EXP2(x) exp2f(x)
#endif

__device__ __forceinline__ u16 f2bf(float f) {  // RNE
  union { float f; unsigned int u; } x; x.f = f;
  unsigned int r = x.u + 0x7fffu + ((x.u >> 16) & 1u);
  return (u16)(r >> 16);
}
__device__ __forceinline__ bf16x8 pack8(float4 a, float4 b) {
  bf16x8 r;
  r[0] = (short)f2bf(a.x); r[1] = (short)f2bf(a.y);
  r[2] = (short)f2bf(a.z); r[3] = (short)f2bf(a.w);
  r[4] = (short)f2bf(b.x); r[5] = (short)f2bf(b.y);
  r[6] = (short)f2bf(b.z); r[7] = (short)f2bf(b.w);
  return r;
}
__device__ __forceinline__ void gload_lds16(const u16* g, u16* l) {
  __builtin_amdgcn_global_load_lds((__attribute__((address_space(1))) void*)g,
                                   (__attribute__((address_space(3))) void*)l, 16, 0, 0);
}

template <int CPR>
__device__ __forceinline__ int sw_off(int r, int c) {
  return (r * CPR + (c ^ (r & (CPR - 1)))) * 8;
}

// ---- fused prep: x->bf16 + Wo transpose + Wq/Wk/Wv transpose (hs=16 path) ----
__global__ __launch_bounds__(1024) void prep(
    const float* __restrict__ x, u16* __restrict__ xb,
    const float* __restrict__ Wq, const float* __restrict__ Wk,
    const float* __restrict__ Wv, const float* __restrict__ Wo,
    u16* __restrict__ WoT, u16* __restrict__ WT3) {
  const int bxg = blockIdx.x, by = blockIdx.y;
  if (bxg >= 128) {
    const int blk = (bxg - 128) * 32 + by;  // 0..511
    const int tid = threadIdx.y * 32 + threadIdx.x;
    const size_t i = ((size_t)blk * 1024 + tid) * 8;
    const float4 a = *(const float4*)&x[i];
    const float4 b2 = *(const float4*)&x[i + 4];
    *(bf16x8*)&xb[i] = pack8(a, b2);
    return;
  }
  __shared__ u16 t[32][33];
  const float* W;
  u16* T;
  int j0, wcol;
  if (bxg < 32) {
    j0 = bxg * 32; wcol = j0; W = Wo; T = WoT;
  } else {
    j0 = (bxg - 32) * 32;  // 0..3071
    const int g = j0 >> 10;
    W = (g == 0) ? Wq : (g == 1) ? Wk : Wv;
    T = WT3;
    wcol = j0 & 1023;
  }
  const int k0 = by * 32;
  t[threadIdx.y][threadIdx.x] =
      f2bf(W[(size_t)(k0 + threadIdx.y) * 1024 + wcol + threadIdx.x]);
  __syncthreads();
  T[(size_t)(j0 + threadIdx.y) * 1024 + k0 + threadIdx.x] = t[threadIdx.x][threadIdx.y];
}

// ---- fallback-path helpers (hs<16) ----
__global__ __launch_bounds__(256) void x_to_bf16(const float* __restrict__ x,
                                                 u16* __restrict__ xb) {
  const size_t i = ((size_t)blockIdx.x * 256 + threadIdx.x) * 8;
  const float4 a = *(const float4*)&x[i];
  const float4 b = *(const float4*)&x[i + 4];
  *(bf16x8*)&xb[i] = pack8(a, b);
}

__global__ void transpose_cols(const float* __restrict__ W0, const float* __restrict__ W1,
                               const float* __restrict__ W2, u16* __restrict__ T,
                               int h0, int hsx64) {
  __shared__ u16 t[32][33];
  const int j0 = blockIdx.x * 32;
  const int g = j0 / hsx64;
  const float* W = (g == 0) ? W0 : (g == 1) ? W1 : W2;
  const int wc0 = h0 * 64 + (j0 % hsx64);
  const int k0 = blockIdx.y * 32;
  t[threadIdx.y][threadIdx.x] =
      f2bf(W[(size_t)(k0 + threadIdx.y) * 1024 + wc0 + threadIdx.x]);
  __syncthreads();
  T[(size_t)(j0 + threadIdx.y) * 1024 + k0 + threadIdx.x] = t[threadIdx.x][threadIdx.y];
}

// ---- k2/k4: C = A[M][K] @ BT[N][K]^T, 128x128 tile, dbuf LDS + XCD swizzle ----
template <int MODE, int AF32>
__global__ __launch_bounds__(256, 2) void gemm_bt(
    const void* __restrict__ Av, const u16* __restrict__ BT,
    void* __restrict__ C0v, u16* __restrict__ C1, u16* __restrict__ C2,
    const float* __restrict__ bias, int M, int N, int K, int hs, int h0) {
  __shared__ __align__(16) u16 lsA[2][128 * 32];
  __shared__ __align__(16) u16 lsB[2][128 * 32];
  const int tid = threadIdx.x, lane = tid & 63, wv = tid >> 6;
  const int quad = lane >> 4, l16 = lane & 15;
  // XCD-chunk swizzle (bijective when nwg%8==0): each XCD gets a contiguous
  // run of linear ids -> with x-fast order, full m-rows per XCD share
  // A-row-panels in that XCD's L2.  [r10: FETCH 40->28.8MB]
  const int nwg = gridDim.x * gridDim.y;
  int lin = blockIdx.y * gridDim.x + blockIdx.x;
  if ((nwg & 7) == 0) lin = (lin & 7) * (nwg >> 3) + (lin >> 3);
  const int m0 = (lin / gridDim.x) * 128, n0 = (lin % gridDim.x) * 128;
  const int wm = (wv >> 1) * 64, wn = (wv & 1) * 64;
  const int hs64 = hs * 64;
  f32x4 acc[4][4] = {};

  if constexpr (!AF32) {
    // prologue: stage tile 0 -> buf 0
#pragma unroll
    for (int c = 0; c < 2; ++c) {
      const int P = c * 256 + tid, r = P >> 2;
      const int gcol = ((P & 3) ^ (r & 3)) * 8;
      gload_lds16((const u16*)Av + (size_t)(m0 + r) * K + gcol,
                  &lsA[0][(c * 256 + wv * 64) * 8]);
      gload_lds16(BT + (size_t)(n0 + r) * K + gcol,
                  &lsB[0][(c * 256 + wv * 64) * 8]);
    }
    __syncthreads();  // tile 0 landed
    const int nk = K >> 5;
    for (int kt = 0; kt < nk; ++kt) {
      const int buf = kt & 1;
      if (kt + 1 < nk) {  // issue DMA for tile kt+1 into buf^1 BEFORE compute
        const int k1 = (kt + 1) << 5;
#pragma unroll
        for (int c = 0; c < 2; ++c) {
          const int P = c * 256 + tid, r = P >> 2;
          const int gcol = ((P & 3) ^ (r & 3)) * 8;
          gload_lds16((const u16*)Av + (size_t)(m0 + r) * K + k1 + gcol,
                      &lsA[buf ^ 1][(c * 256 + wv * 64) * 8]);
          gload_lds16(BT + (size_t)(n0 + r) * K + k1 + gcol,
                      &lsB[buf ^ 1][(c * 256 + wv * 64) * 8]);
        }
      }
      bf16x8 af[4], bfr[4];
#pragma unroll
      for (int i = 0; i < 4; ++i)
        af[i] = *(const bf16x8*)&lsA[buf][sw_off<4>(wm + i * 16 + l16, quad)];
#pragma unroll
      for (int j = 0; j < 4; ++j)
        bfr[j] = *(const bf16x8*)&lsB[buf][sw_off<4>(wn + j * 16 + l16, quad)];
#pragma unroll
      for (int i = 0; i < 4; ++i)
#pragma unroll
        for (int j = 0; j < 4; ++j) acc[i][j] = MFMA_BF16(af[i], bfr[j], acc[i][j]);
      __syncthreads();  // drains vmcnt (tile kt+1 landed) + all reads of buf done
    }
  } else {
    // fallback reg-staged path (hs<16 only), single-buffered
    for (int k0 = 0; k0 < K; k0 += 32) {
      bf16x8 va[2], vb[2];
#pragma unroll
      for (int c = 0; c < 2; ++c) {
        const int P = c * 256 + tid, r = P >> 2, cc = P & 3;
        const float* Af = (const float*)Av;
        const float4 a0 = *(const float4*)&Af[(size_t)(m0 + r) * K + k0 + cc * 8];
        const float4 a1 = *(const float4*)&Af[(size_t)(m0 + r) * K + k0 + cc * 8 + 4];
        va[c] = pack8(a0, a1);
        vb[c] = *(const bf16x8*)&BT[(size_t)(n0 + r) * K + k0 + cc * 8];
      }
      __syncthreads();
#pragma unroll
      for (int c = 0; c < 2; ++c) {
        const int P = c * 256 + tid, r = P >> 2, cc = P & 3;
        *(bf16x8*)&lsA[0][sw_off<4>(r, cc)] = va[c];
        *(bf16x8*)&lsB[0][sw_off<4>(r, cc)] = vb[c];
      }
      __syncthreads();
      bf16x8 af[4], bfr[4];
#pragma unroll
      for (int i = 0; i < 4; ++i)
        af[i] = *(const bf16x8*)&lsA[0][sw_off<4>(wm + i * 16 + l16, quad)];
#pragma unroll
      for (int j = 0; j < 4; ++j)
        bfr[j] = *(const bf16x8*)&lsB[0][sw_off<4>(wn + j * 16 + l16, quad)];
#pragma unroll
      for (int i = 0; i < 4; ++i)
#pragma unroll
        for (int j = 0; j < 4; ++j) acc[i][j] = MFMA_BF16(af[i], bfr[j], acc[i][j]);
    }
  }

  if constexpr (MODE == 3) {
#pragma unroll
    for (int j = 0; j < 4; ++j) {
      const int n = n0 + wn + j * 16 + l16;  // region constant over i,r
#pragma unroll
      for (int i = 0; i < 4; ++i) {
        const int mb = m0 + wm + i * 16 + quad * 4;  // 4-aligned, no 2048-cross
        const int b = mb >> 11, s0 = mb & 2047;
        if (n < hs64) {
#pragma unroll
          for (int r = 0; r < 4; ++r)
            ((u16*)C0v)[((size_t)b * 2048 + s0 + r) * hs64 + n] =
                f2bf(acc[i][j][r] * QSCALE);
        } else if (n < 2 * hs64) {
#pragma unroll
          for (int r = 0; r < 4; ++r)
            C1[((size_t)b * 2048 + s0 + r) * hs64 + (n - hs64)] = f2bf(acc[i][j][r]);
        } else {
          const int nn = n - 2 * hs64;  // V: r-adjacent = s-consecutive -> pack 8B
          uint2 o;
          o.x = (unsigned)f2bf(acc[i][j][0]) | ((unsigned)f2bf(acc[i][j][1]) << 16);
          o.y = (unsigned)f2bf(acc[i][j][2]) | ((unsigned)f2bf(acc[i][j][3]) << 16);
          *(uint2*)&C2[((size_t)(b * hs + (nn >> 6)) * 64 + (nn & 63)) * 2048 + s0] = o;
        }
      }
    }
  } else {
#pragma unroll
    for (int i = 0; i < 4; ++i)
#pragma unroll
      for (int j = 0; j < 4; ++j) {
        const int n = n0 + wn + j * 16 + l16;
        float bv = 0.f;
        if constexpr (MODE == 1) bv = bias[n];
#pragma unroll
        for (int r = 0; r < 4; ++r) {
          const int m = m0 + wm + i * 16 + quad * 4 + r;
          const int b = (m >= hs * 128) ? 1 : 0;
          const int rp = m - b * hs * 128;
          ((float*)C0v)[(size_t)(b * 2048 + h0 * 128 + rp) * 1024 + n] =
              acc[i][j][r] + bv;
        }
      }
  }
}

// ---- k3: attn v13 (v12 pipeline + T5 setprio) ----
__global__ __launch_bounds__(256, 2) void attn_fwd(
    const u16* __restrict__ Qsl, const u16* __restrict__ Ksl,
    const u16* __restrict__ VTsl, u16* __restrict__ A2sl, int hs) {
  __shared__ __align__(16) u16 lsK[3][64 * 64];  // [key][hd] CPR=8; [0..1] dead
                                                 // after kt loop -> f32 O scratch
  __shared__ __align__(16) u16 lsV[3][64 * 64];  // [hd][key] CPR=8
  __shared__ __align__(16) u16 lsP[4][16 * 64];  // per-wave P^T, 128B rows, XOR-swz
  __shared__ __align__(16) float scrl[64];
  const int tid = threadIdx.x, lane = tid & 63, wv = tid >> 6;
  const int quad = lane >> 4, l16 = lane & 15;
  const int grp = wv >> 1, wq = wv & 1;

  // bijective XCD-chunk swizzle (gridDim.x % 8 == 0)
  const int cpx = gridDim.x >> 3;
  const int w = (blockIdx.x & 7) * cpx + (blockIdx.x >> 3);
  const int bh = w >> 4, bx = w & 15;

  const int b = (bh >= hs) ? 1 : 0, hh = bh - b * hs;
  const int hs64 = hs * 64;
  const u16* Qb = Qsl + (size_t)b * 2048 * hs64;
  const u16* Kb = Ksl + (size_t)b * 2048 * hs64;
  const u16* Vb = VTsl + (size_t)(b * hs + hh) * 64 * 2048;
  u16* A2b = A2sl + (size_t)(b * hs + hh) * 2048 * 64;
  u16* lsPw = &lsP[wv][0];
  float* scro = (float*)&lsK[0][0];  // 16KB spans lsK[0..1]

  bf16x8 ones;
#pragma unroll
  for (int i = 0; i < 8; ++i) ones[i] = (short)0x3F80;

  const int prow = l16 >> 1;       // lsP row sub-index / XOR mask
  const int pb0 = (l16 & 1) << 2;  // q&1 selects 32-u16 half of the 128B row

  // constant per-thread staging geometry
  const int Pa = tid, ra = Pa >> 3, ca = (Pa & 7) ^ (ra & 7);
  const int Pb2 = 256 + tid, rb = Pb2 >> 3, cb = (Pb2 & 7) ^ (rb & 7);
  const size_t kTileStep = (size_t)64 * hs64;
  const u16* const kBa = Kb + (size_t)ra * hs64 + hh * 64 + ca * 8;
  const u16* const kBb = Kb + (size_t)rb * hs64 + hh * 64 + cb * 8;
  const u16* const vBa = Vb + (size_t)ra * 2048 + ca * 8;
  const u16* const vBb = Vb + (size_t)rb * 2048 + cb * 8;
  const int dA = (wv * 64) * 8;
  const int dB = (256 + wv * 64) * 8;

  for (int half = 0; half < 2; ++half) {
    const int qt = (half == 0) ? bx : 31 - bx;
    const int q0 = qt * 64;

    bf16x8 qf[2][2];
#pragma unroll
    for (int j = 0; j < 2; ++j)
#pragma unroll
      for (int ks = 0; ks < 2; ++ks)
        qf[j][ks] = *(const bf16x8*)&Qb[(size_t)(q0 + wq * 32 + j * 16 + l16) * hs64 +
                                        hh * 64 + ks * 32 + quad * 8];

    f32x4 acc_o[2][4] = {};
    f32x4 acc_l[2] = {};

    const u16* pkA = kBa;
    const u16* pkB = kBb;
    const u16* pvA = vBa;
    const u16* pvB = vBb;
    int bc = 0, bn = 1, bf_ = 2;

    auto stage = [&](int bs) {  // DMA one K/V tile, advance source pointers
      gload_lds16(pkA, &lsK[bs][dA]);
      gload_lds16(pkB, &lsK[bs][dB]);
      gload_lds16(pvA, &lsV[bs][dA]);
      gload_lds16(pvB, &lsV[bs][dB]);
      pkA += kTileStep; pkB += kTileStep; pvA += 64; pvB += 64;
    };
    auto qk = [&](int bK, f32x4 (&S)[2][2]) {  // S^T = K Q^T
#pragma unroll
      for (int j = 0; j < 2; ++j)
#pragma unroll
        for (int nj = 0; nj < 2; ++nj) S[j][nj] = f32x4{0.f, 0.f, 0.f, 0.f};
      __builtin_amdgcn_s_setprio(1);  // T5: favor MFMA-issuing wave
#pragma unroll
      for (int ks = 0; ks < 2; ++ks)
#pragma unroll
        for (int nj = 0; nj < 2; ++nj) {
          const bf16x8 kf = *(const bf16x8*)
              &lsK[bK][sw_off<8>(grp * 32 + nj * 16 + l16, ks * 4 + quad)];
          S[0][nj] = MFMA_BF16(kf, qf[0][ks], S[0][nj]);
          S[1][nj] = MFMA_BF16(kf, qf[1][ks], S[1][nj]);
        }
      __builtin_amdgcn_s_setprio(0);
    };
    auto smpv = [&](f32x4 (&S)[2][2], int bV, bool domask) {  // softmax + PV + l
#pragma unroll
      for (int j = 0; j < 2; ++j) {
        const int grow = wq * 32 + j * 16 + l16;
#pragma unroll
        for (int nj = 0; nj < 2; ++nj) {
#pragma unroll
          for (int r = 0; r < 4; ++r) {
            float p = EXP2(S[j][nj][r]);
            if (domask) {
              const int keyb = grp * 32 + nj * 16 + quad * 4;
              p = (keyb + r > grow) ? 0.f : p;
            }
            S[j][nj][r] = p;
          }
          union { float f; unsigned int u; } t0, t1, t2, t3;
          t0.f = S[j][nj][0]; t1.f = S[j][nj][1];
          t2.f = S[j][nj][2]; t3.f = S[j][nj][3];
          uint2 wpk;
          wpk.x = (t0.u >> 16) | (t1.u & 0xFFFF0000u);
          wpk.y = (t2.u >> 16) | (t3.u & 0xFFFF0000u);
          const int row = j * 8 + prow;
          const int chunk = (pb0 + 2 * nj + (quad >> 1)) ^ prow;
          *(uint2*)&lsPw[row * 64 + chunk * 8 + (quad & 1) * 4] = wpk;
        }
      }
      bf16x8 pf[2];
#pragma unroll
      for (int j = 0; j < 2; ++j) {
        const int row = j * 8 + prow;
        const int chunk = (pb0 + quad) ^ prow;
        pf[j] = *(const bf16x8*)&lsPw[row * 64 + chunk * 8];
      }
      __builtin_amdgcn_s_setprio(1);  // T5: l + PV MFMA cluster
#pragma unroll
      for (int j = 0; j < 2; ++j) acc_l[j] = MFMA_BF16(ones, pf[j], acc_l[j]);
#pragma unroll
      for (int njo = 0; njo < 4; ++njo) {
        const bf16x8 vf = *(const bf16x8*)
            &lsV[bV][sw_off<8>(njo * 16 + l16, grp * 4 + quad)];
        acc_o[0][njo] = MFMA_BF16(vf, pf[0], acc_o[0][njo]);
        acc_o[1][njo] = MFMA_BF16(vf, pf[1], acc_o[1][njo]);
      }
      __builtin_amdgcn_s_setprio(0);
    };
    // one pipelined iteration: Sc = S(kt) ready; computes S(kt+1) into Sn
    auto step = [&](f32x4 (&Sc)[2][2], f32x4 (&Sn)[2][2], int kt) {
      __syncthreads();                 // DMA(kt+1) landed in bn; bf_ reads done
      if (kt + 2 <= qt) stage(bf_);    // DMA(kt+2) -> bf_, in flight this iter
      qk(bn, Sn);                      // QK(kt+1): DS+MFMA
      smpv(Sc, bc, false);             // softmax(kt): VALU (indep) + PV(kt)
      const int t = bc; bc = bn; bn = bf_; bf_ = t;
    };

    __syncthreads();   // prev half fully consumed (incl. scro region)
    stage(0);          // tile 0 -> buf 0
    __syncthreads();   // tile 0 landed
    if (qt >= 1) stage(1);  // tile 1 -> buf 1, in flight under QK(0)

    f32x4 sA[2][2], sB[2][2];
    qk(0, sA);  // S(0)

    int kt = 0;
    while (kt + 1 < qt) { step(sA, sB, kt); step(sB, sA, kt + 1); kt += 2; }
    bool curA = true;
    if (kt < qt) { step(sA, sB, kt); curA = false; }
    // tail: diagonal tile qt (masked); V(qt) is in bc after rotation
    if (curA) smpv(sA, bc, true); else smpv(sB, bc, true);

    // combine: exact partial sums (no-max softmax needs no rescale)
    __syncthreads();  // all lsK/lsV reads done -> scro region free
    if (grp == 1) {
#pragma unroll
      for (int j = 0; j < 2; ++j) {
#pragma unroll
        for (int njo = 0; njo < 4; ++njo) {
          const int ch = (njo * 4 + quad) ^ l16;
          *(f32x4*)&scro[(size_t)(wq * 32 + j * 16 + l16) * 64 + ch * 4] =
              acc_o[j][njo];
        }
        if (quad == 0) scrl[wq * 32 + j * 16 + l16] = acc_l[j][0];
      }
    }
    __syncthreads();
    if (grp == 0) {
#pragma unroll
      for (int j = 0; j < 2; ++j) {
        const int ql = wq * 32 + j * 16 + l16;
        const float inv = 1.0f / (acc_l[j][0] + scrl[ql]);
#pragma unroll
        for (int njo = 0; njo < 4; ++njo) {
          const int ch = (njo * 4 + quad) ^ l16;
          const f32x4 ob = *(const f32x4*)&scro[(size_t)ql * 64 + ch * 4];
          uint2 o;
          o.x = (unsigned)f2bf((acc_o[j][njo][0] + ob[0]) * inv) |
                ((unsigned)f2bf((acc_o[j][njo][1] + ob[1]) * inv) << 16);
          o.y = (unsigned)f2bf((acc_o[j][njo][2] + ob[2]) * inv) |
                ((unsigned)f2bf((acc_o[j][njo][3] + ob[3]) * inv) << 16);
          *(uint2*)&A2b[(size_t)(q0 + ql) * 64 + njo * 16 + quad * 4] = o;
        }
      }
    }
  }
}

// ---------------- launcher ----------------
extern "C" void kernel_launch(void* const* d_in, const int* in_sizes, int n_in,
                              void* d_out, int out_size, void* d_ws, size_t ws_size,
                              hipStream_t stream) {
  (void)in_sizes; (void)n_in; (void)out_size;
  const float* x  = (const float*)d_in[0];
  const float* Wq = (const float*)d_in[1];
  const float* Wk = (const float*)d_in[2];
  const float* Wv = (const float*)d_in[3];
  const float* Wo = (const float*)d_in[4];
  const float* bo = (const float*)d_in[5];
  float* out = (float*)d_out;
  char* ws = (char*)d_ws;
  const size_t MB = 1024 * 1024;
  const size_t KB = 1024;

  int hs = 2;
  if      (ws_size >= 2 * MB + 16 * 2432 * KB) hs = 16;
  else if (ws_size >= 2 * MB +  8 * 2432 * KB) hs = 8;
  else if (ws_size >= 2 * MB +  4 * 2432 * KB) hs = 4;

  u16* WoT   = (u16*)(ws);
  u16* Ksl   = (u16*)(ws + 2 * MB);
  u16* VTsl  = (u16*)(ws + 2 * MB + (size_t)hs *  512 * KB);
  u16* A2sl  = (u16*)(ws + 2 * MB + (size_t)hs * 1024 * KB);
  u16* WT3sl = (u16*)(ws + 2 * MB + (size_t)hs * 1536 * KB);
  u16* Qsl   = (u16*)(ws + 2 * MB + (size_t)hs * 1920 * KB);

  if (hs == 16) {
    u16* xb = A2sl;  // aliases A2sl: consumed by k2, overwritten by k3
    prep<<<dim3(144, 32), dim3(32, 32), 0, stream>>>(x, xb, Wq, Wk, Wv, Wo, WoT, WT3sl);
    gemm_bt<3, 0><<<dim3(24, 32), 256, 0, stream>>>(
        (const void*)xb, WT3sl, (void*)Qsl, Ksl, VTsl, nullptr, 4096, 3072, 1024, 16, 0);
    attn_fwd<<<dim3(512), 256, 0, stream>>>(Qsl, Ksl, VTsl, A2sl, 16);
    gemm_bt<1, 0><<<dim3(8, 32), 256, 0, stream>>>(
        (const void*)A2sl, WoT, (void*)out, nullptr, nullptr, bo, 4096, 1024, 1024, 16, 0);
  } else {
    transpose_cols<<<dim3(32, 32), dim3(32, 32), 0, stream>>>(Wo, Wo, Wo, WoT, 0, 1024);
    for (int h0 = 0; h0 < 16; h0 += hs) {
      transpose_cols<<<dim3(6 * hs, 32), dim3(32, 32), 0, stream>>>(Wq, Wk, Wv, WT3sl, h0, hs * 64);
      gemm_bt<3, 1><<<dim3((3 * hs) / 2, 32), 256, 0, stream>>>(
          (const void*)x, WT3sl, (void*)Qsl, Ksl, VTsl, nullptr, 4096, 3 * hs * 64, 1024, hs, h0);
      attn_fwd<<<dim3(16 * 2 * hs), 256, 0, stream>>>(Qsl, Ksl, VTsl, A2sl, hs);
      gemm_bt<1, 0><<<dim3(8, 2 * hs), 256, 0, stream>>>(
          (const void*)A2sl, WoT, (void*)out, nullptr, nullptr, bo, 2 * hs * 128, 1024, 1024, hs, h0);
    }
  }
}